// Round 9
// baseline (298.647 us; speedup 1.0000x reference)
//
#include <hip/hip_runtime.h>
#include <stdint.h>
#include <stddef.h>

// ---------------------------------------------------------------------------
// Types / helpers
// ---------------------------------------------------------------------------
using bf16x8 = __attribute__((ext_vector_type(8))) __bf16;
using f32x4  = __attribute__((ext_vector_type(4))) float;
using f32x16 = __attribute__((ext_vector_type(16))) float;

__device__ __forceinline__ float bf2f(unsigned short u) {
  union { unsigned int i; float f; } v; v.i = ((unsigned int)u) << 16; return v.f;
}
__device__ __forceinline__ unsigned short f2bf(float f) {
  union { float f; unsigned int i; } v; v.f = f;
  unsigned int r = v.i + 0x7fffu + ((v.i >> 16) & 1u);   // RNE
  return (unsigned short)(r >> 16);
}
__device__ __forceinline__ unsigned short f2bf_trunc(float f) {
  union { float f; unsigned int i; } v; v.f = f;
  return (unsigned short)(v.i >> 16);
}
// pack two f32 -> u32 of two truncated bf16 (lo = a, hi = b)
__device__ __forceinline__ unsigned int pk_trunc(float a, float b) {
  union { float f; unsigned int i; } x, y; x.f = a; y.f = b;
  return (x.i >> 16) | (y.i & 0xffff0000u);
}
__device__ __forceinline__ bf16x8 mk_bf16x8(unsigned int a, unsigned int b,
                                            unsigned int c, unsigned int d) {
  union { unsigned int u[4]; bf16x8 v; } x;
  x.u[0] = a; x.u[1] = b; x.u[2] = c; x.u[3] = d; return x.v;
}
// async global->LDS, 16 B/lane; LDS dest must be wave-uniform base + lane*16.
__device__ __forceinline__ void async16(const void* g, void* l) {
  __builtin_amdgcn_global_load_lds(
      (const __attribute__((address_space(1))) unsigned int*)g,
      (__attribute__((address_space(3))) unsigned int*)l, 16, 0, 0);
}

#define S_LEN 2048
#define DMODEL 1024
#define NHEAD 16
#define DHEAD 64
#define DFFN 4096

// ---------------------------------------------------------------------------
// prep_k: fused weight transposes (64x64 vectorized tiles) + rmsnorm(x)->Hin.
// ---------------------------------------------------------------------------
struct PrepArgs {
  const float *wq, *wk, *wv, *wo, *w1, *w3, *w2, *x, *anw;
  unsigned short *WqkvT, *WoT, *W13I, *W2T, *Hin;
};
__global__ __launch_bounds__(256) void prep_k(PrepArgs a) {
  __shared__ unsigned short tile[64][66];
  __shared__ float red[4];
  const int bid = blockIdx.x;
  const int t = threadIdx.x;

  if (bid < 4096) {
    const float* in;
    unsigned short* out;
    int src_ld, dst_ld, bx, by;
    bool w13 = false;
    int rb = 0;
    if (bid < 1024) {
      int z = bid >> 8, rem = bid & 255;
      bx = rem & 15; by = rem >> 4;
      in = z == 0 ? a.wq : z == 1 ? a.wk : z == 2 ? a.wv : a.wo;
      out = z == 0 ? a.WqkvT : z == 1 ? a.WqkvT + 1048576 : z == 2 ? a.WqkvT + 2097152 : a.WoT;
      src_ld = 1024; dst_ld = 1024;
    } else if (bid < 3072) {
      int r = bid - 1024;
      int z = r >> 10, rem = r & 1023;
      bx = rem & 63; by = rem >> 6;
      in = z ? a.w3 : a.w1;
      out = a.W13I;
      src_ld = 4096; dst_ld = 1024;
      w13 = true; rb = z * 32;
    } else {
      int r = bid - 3072;
      bx = r & 15; by = r >> 4;
      in = a.w2; out = a.W2T;
      src_ld = 1024; dst_ld = 4096;
    }
    const int br = by * 64, bc = bx * 64;
    const int rr = t >> 4, c4 = (t & 15) * 4;
#pragma unroll
    for (int i = 0; i < 4; ++i) {
      int row = rr + i * 16;
      float4 v = *(const float4*)&in[(size_t)(br + row) * src_ld + bc + c4];
      tile[row][c4 + 0] = f2bf(v.x);
      tile[row][c4 + 1] = f2bf(v.y);
      tile[row][c4 + 2] = f2bf(v.z);
      tile[row][c4 + 3] = f2bf(v.w);
    }
    __syncthreads();
    const int x = t >> 2, y16 = (t & 3) * 16;
    int dest = bc + x;
    if (w13) dest = (bc >> 5) * 64 + (x >> 5) * 64 + rb + (x & 31);
#pragma unroll
    for (int i = 0; i < 2; ++i) {
      int y0 = y16 + i * 8;
      ushort4 o0, o1;
      o0.x = tile[y0 + 0][x]; o0.y = tile[y0 + 1][x];
      o0.z = tile[y0 + 2][x]; o0.w = tile[y0 + 3][x];
      o1.x = tile[y0 + 4][x]; o1.y = tile[y0 + 5][x];
      o1.z = tile[y0 + 6][x]; o1.w = tile[y0 + 7][x];
      *(ushort4*)&out[(size_t)dest * dst_ld + br + y0] = o0;
      *(ushort4*)&out[(size_t)dest * dst_ld + br + y0 + 4] = o1;
    }
  } else {
    // rmsnorm row
    const int row = bid - 4096;
    const int lane = t & 63, w = t >> 6;
    const float* x = a.x + (size_t)row * DMODEL;
    float xs[4];
    float s = 0.f;
#pragma unroll
    for (int i = 0; i < 4; ++i) {
      xs[i] = x[t * 4 + i];
      s += xs[i] * xs[i];
    }
#pragma unroll
    for (int m = 1; m < 64; m <<= 1) s += __shfl_xor(s, m, 64);
    if (lane == 0) red[w] = s;
    __syncthreads();
    float tot = red[0] + red[1] + red[2] + red[3];
    float inv = rsqrtf(tot * (1.0f / DMODEL) + 1e-6f);
#pragma unroll
    for (int i = 0; i < 4; ++i)
      a.Hin[(size_t)row * DMODEL + t * 4 + i] = f2bf(xs[i] * inv * a.anw[t * 4 + i]);
  }
}

// ---------------------------------------------------------------------------
// rope_vtrans_k: fused RoPE (bid<4096) + V-transpose (bid>=4096).
// ---------------------------------------------------------------------------
__global__ __launch_bounds__(256) void rope_vtrans_k(
    unsigned short* __restrict__ QKV,
    const float* __restrict__ cosp,
    const float* __restrict__ sinp,
    unsigned short* __restrict__ VtG) {
  __shared__ unsigned short tile[64][66];
  const int bid = blockIdx.x;
  const int t = threadIdx.x;
  if (bid < 4096) {
    int idx = bid * 256 + t;
    int s = idx >> 9;
    int rem = idx & 511;
    int h = rem >> 5;
    int i = rem & 31;
    float c = cosp[s * 32 + i];
    float sn = sinp[s * 32 + i];
    size_t off = (size_t)s * 3072 + h * 64 + 2 * i;
    {
      float e = bf2f(QKV[off]), o = bf2f(QKV[off + 1]);
      QKV[off] = f2bf(e * c - o * sn);
      QKV[off + 1] = f2bf(e * sn + o * c);
    }
    {
      float e = bf2f(QKV[off + 1024]), o = bf2f(QKV[off + 1025]);
      QKV[off + 1024] = f2bf((e * c - o * sn) * 0.125f);
      QKV[off + 1025] = f2bf((e * sn + o * c) * 0.125f);
    }
  } else {
    int r = bid - 4096;
    const int bx = r & 15, by = r >> 4;
    const int br = by * 64, bc = bx * 64;
    const int rr = t >> 4, c4 = (t & 15) * 4;
#pragma unroll
    for (int i = 0; i < 4; ++i) {
      int row = rr + i * 16;
      ushort4 v = *(const ushort4*)&QKV[(size_t)(br + row) * 3072 + 2048 + bc + c4];
      tile[row][c4 + 0] = v.x;
      tile[row][c4 + 1] = v.y;
      tile[row][c4 + 2] = v.z;
      tile[row][c4 + 3] = v.w;
    }
    __syncthreads();
    const int x = t >> 2, y16 = (t & 3) * 16;
#pragma unroll
    for (int i = 0; i < 2; ++i) {
      int y0 = y16 + i * 8;
      ushort4 o0, o1;
      o0.x = tile[y0 + 0][x]; o0.y = tile[y0 + 1][x];
      o0.z = tile[y0 + 2][x]; o0.w = tile[y0 + 3][x];
      o1.x = tile[y0 + 4][x]; o1.y = tile[y0 + 5][x];
      o1.z = tile[y0 + 6][x]; o1.w = tile[y0 + 7][x];
      *(ushort4*)&VtG[(size_t)(bc + x) * 2048 + br + y0] = o0;
      *(ushort4*)&VtG[(size_t)(bc + x) * 2048 + br + y0 + 4] = o1;
    }
  }
}

// ---------------------------------------------------------------------------
// GEMM C = A[M,K](bf16) @ BT[N,K](bf16)^T, f32 accum.
// 128x128 tile, BK=64, mfma_32x32x16, async16 staging.
// ---------------------------------------------------------------------------
template <int MODE>
__global__ __launch_bounds__(256) void gemm_bt(
    const unsigned short* __restrict__ A, int lda,
    const unsigned short* __restrict__ BT,
    void* __restrict__ Cout,
    int K, int N) {
  __shared__ unsigned short As[128 * 64];
  __shared__ unsigned short Bs[128 * 64];
  const int t = threadIdx.x;
  const int lane = t & 63;
  const int w = t >> 6;
  const int qr = (w >> 1) * 64, qc = (w & 1) * 64;
  const int l31 = lane & 31, half = lane >> 5;
  const int m0 = blockIdx.y * 128, n0 = blockIdx.x * 128;

  f32x16 acc[2][2] = {};

  int srow[4], scol[4];
#pragma unroll
  for (int p = 0; p < 4; ++p) {
    int off = p * 2048 + t * 8;
    int r = off >> 6;
    srow[p] = r;
    scol[p] = ((((off >> 3) & 7) ^ (r & 7) ^ ((r >> 3) & 3))) * 8;
  }
  const int gsw = (l31 & 7) ^ (l31 >> 3);

  for (int k0 = 0; k0 < K; k0 += 64) {
    __syncthreads();
#pragma unroll
    for (int p = 0; p < 4; ++p) {
      int off = p * 2048 + t * 8;
      async16(A + (size_t)(m0 + srow[p]) * lda + (k0 + scol[p]), &As[off]);
      async16(BT + (size_t)(n0 + srow[p]) * K + (k0 + scol[p]), &Bs[off]);
    }
    __syncthreads();
#pragma unroll
    for (int ks = 0; ks < 4; ++ks) {
      const int ch = ((ks * 2 + half) ^ gsw) * 8;
      bf16x8 a0 = *(const bf16x8*)&As[(qr + l31) * 64 + ch];
      bf16x8 a1 = *(const bf16x8*)&As[(qr + 32 + l31) * 64 + ch];
      bf16x8 b0 = *(const bf16x8*)&Bs[(qc + l31) * 64 + ch];
      bf16x8 b1 = *(const bf16x8*)&Bs[(qc + 32 + l31) * 64 + ch];
      acc[0][0] = __builtin_amdgcn_mfma_f32_32x32x16_bf16(a0, b0, acc[0][0], 0, 0, 0);
      acc[0][1] = __builtin_amdgcn_mfma_f32_32x32x16_bf16(a0, b1, acc[0][1], 0, 0, 0);
      acc[1][0] = __builtin_amdgcn_mfma_f32_32x32x16_bf16(a1, b0, acc[1][0], 0, 0, 0);
      acc[1][1] = __builtin_amdgcn_mfma_f32_32x32x16_bf16(a1, b1, acc[1][1], 0, 0, 0);
    }
  }

  // C/D layout: col = lane&31, row = (reg&3) + 8*(reg>>2) + 4*half
  {
    unsigned short* C = (unsigned short*)Cout;
#pragma unroll
    for (int rt = 0; rt < 2; ++rt)
#pragma unroll
      for (int ct = 0; ct < 2; ++ct)
#pragma unroll
        for (int reg = 0; reg < 16; ++reg) {
          int rr = m0 + qr + rt * 32 + (reg & 3) + 8 * (reg >> 2) + 4 * half;
          int cc = n0 + qc + ct * 32 + l31;
          C[(size_t)rr * N + cc] = f2bf(acc[rt][ct][reg]);
        }
  }
}

// ---------------------------------------------------------------------------
// FFN w1/w3 gated GEMM, 256x256 tile, BK=64, 8 waves (2M x 4N), 8-phase.
// The R2 structure + old row&7 swizzle. (Per-session clock-state varies
// absolute dispatch times 1.4x; only e2e / within-session deltas count.)
// ---------------------------------------------------------------------------
__device__ __forceinline__ void mfma8(f32x16& c0, f32x16& c1,
                                      const bf16x8 (&a)[2][4],
                                      const bf16x8 (&b)[4]) {
  __builtin_amdgcn_s_setprio(1);
#pragma unroll
  for (int ks = 0; ks < 4; ++ks) {
    c0 = __builtin_amdgcn_mfma_f32_32x32x16_bf16(a[0][ks], b[ks], c0, 0, 0, 0);
    c1 = __builtin_amdgcn_mfma_f32_32x32x16_bf16(a[1][ks], b[ks], c1, 0, 0, 0);
  }
  __builtin_amdgcn_s_setprio(0);
}

__global__ __launch_bounds__(512, 2) void gemm256_silu(
    const unsigned short* __restrict__ A,   // Hin [2048][1024]
    const unsigned short* __restrict__ BT,  // W13I [8192][1024]
    unsigned short* __restrict__ F) {       // out  [2048][4096]
  __shared__ unsigned short lds[65536];     // 128 KiB: [d][As 16384 | Bs 16384]
  const int t = threadIdx.x;
  const int l = t & 63, l31 = l & 31, half = l >> 5;
  const int w = t >> 6;
  const int wm = w >> 2, wn = w & 3;

  const int orig = blockIdx.x;
  const int bx = (orig & 7) * 4 + ((orig >> 3) & 3);
  const int by = orig >> 5;
  const int m0 = by * 256, n0 = bx * 256;

  const int rA = t >> 3;                              // row within 64-row block
  const int sc = ((t & 7) ^ ((t >> 3) & 7)) * 8;      // swizzled k-chunk col
  const int lo = t * 8;                               // lds elems within 4096

#define STAGE_A(h, tile, d)                                                    \
  { async16(A + (size_t)(m0 + (h) * 128 + rA) * 1024 + (tile) * 64 + sc,       \
            &lds[(d) * 32768 + (h) * 8192 + lo]);                              \
    async16(A + (size_t)(m0 + (h) * 128 + 64 + rA) * 1024 + (tile) * 64 + sc,  \
            &lds[(d) * 32768 + (h) * 8192 + 4096 + lo]); }
#define STAGE_B(h, tile, d)                                                    \
  { async16(BT + (size_t)(n0 + (h) * 128 + rA) * 1024 + (tile) * 64 + sc,      \
            &lds[(d) * 32768 + 16384 + (h) * 8192 + lo]);                      \
    async16(BT + (size_t)(n0 + (h) * 128 + 64 + rA) * 1024 + (tile) * 64 + sc, \
            &lds[(d) * 32768 + 16384 + (h) * 8192 + 4096 + lo]); }

  const int arow = wm * 128 + l31;
  const int brow = wn * 64 + l31;
  int kc[4];
#pragma unroll
  for (int ks = 0; ks < 4; ++ks) kc[ks] = ((ks * 2 + half) ^ (l31 & 7)) * 8;

#define LDA(d, mt, ks) (*(const bf16x8*)&lds[(d) * 32768 + (arow + (mt) * 32) * 64 + kc[ks]])
#define LDB(d, nt, ks) (*(const bf16x8*)&lds[(d) * 32768 + 16384 + (brow + (nt) * 32) * 64 + kc[ks]])

  f32x16 acc[4][2] = {};
  bf16x8 afr[2][4], bfr[2][4];

  // prologue: tile0 all 4 halves -> dbuf0; tile1.A0+A1 -> dbuf1
  STAGE_A(0, 0, 0); STAGE_A(1, 0, 0); STAGE_B(0, 0, 0); STAGE_B(1, 0, 0);
  STAGE_A(0, 1, 1); STAGE_A(1, 1, 1);
  asm volatile("s_waitcnt vmcnt(4)" ::: "memory");
  __builtin_amdgcn_s_barrier();

#pragma unroll 1
  for (int i = 0; i < 8; ++i) {
    const int t1 = 2 * i + 1, t2 = 2 * i + 2, t3 = 2 * i + 3;
    const bool more = i < 7;

    // ---- P1: read dbuf0 A[0,1],B[0]; stage t1.B0 -> dbuf1
#pragma unroll
    for (int ks = 0; ks < 4; ++ks) {
      afr[0][ks] = LDA(0, 0, ks);
      afr[1][ks] = LDA(0, 1, ks);
      bfr[0][ks] = LDB(0, 0, ks);
    }
    STAGE_B(0, t1, 1);
    __builtin_amdgcn_s_barrier();
    mfma8(acc[0][0], acc[1][0], afr, bfr[0]);
    __builtin_amdgcn_s_barrier();

    // ---- P2: read B[1]; stage t1.B1 -> dbuf1
#pragma unroll
    for (int ks = 0; ks < 4; ++ks) bfr[1][ks] = LDB(0, 1, ks);
    STAGE_B(1, t1, 1);
    __builtin_amdgcn_s_barrier();
    mfma8(acc[0][1], acc[1][1], afr, bfr[1]);
    __builtin_amdgcn_s_barrier();

    // ---- P3: read A[2,3]; stage t2.B0 -> dbuf0
#pragma unroll
    for (int ks = 0; ks < 4; ++ks) {
      afr[0][ks] = LDA(0, 2, ks);
      afr[1][ks] = LDA(0, 3, ks);
    }
    if (more) STAGE_B(0, t2, 0);
    __builtin_amdgcn_s_barrier();
    mfma8(acc[2][0], acc[3][0], afr, bfr[0]);
    __builtin_amdgcn_s_barrier();

    // ---- P4: stage t2.B1 + t2.A0 -> dbuf0; GATE t1.{A,B0}
    if (more) {
      STAGE_B(1, t2, 0);
      STAGE_A(0, t2, 0);
      asm volatile("s_waitcnt vmcnt(8)" ::: "memory");
    } else {
      asm volatile("s_waitcnt vmcnt(2)" ::: "memory");
    }
    __builtin_amdgcn_s_barrier();
    mfma8(acc[2][1], acc[3][1], afr, bfr[1]);
    __builtin_amdgcn_s_barrier();

    // ---- P5: read dbuf1 A[0,1],B[0]; stage t2.A1 -> dbuf0; GATE t1.B1
#pragma unroll
    for (int ks = 0; ks < 4; ++ks) {
      afr[0][ks] = LDA(1, 0, ks);
      afr[1][ks] = LDA(1, 1, ks);
      bfr[0][ks] = LDB(1, 0, ks);
    }
    if (more) {
      STAGE_A(1, t2, 0);
      asm volatile("s_waitcnt vmcnt(8)" ::: "memory");
    } else {
      asm volatile("s_waitcnt vmcnt(0)" ::: "memory");
    }
    __builtin_amdgcn_s_barrier();
    mfma8(acc[0][0], acc[1][0], afr, bfr[0]);
    __builtin_amdgcn_s_barrier();

    // ---- P6: read B[1]
#pragma unroll
    for (int ks = 0; ks < 4; ++ks) bfr[1][ks] = LDB(1, 1, ks);
    __builtin_amdgcn_s_barrier();
    mfma8(acc[0][1], acc[1][1], afr, bfr[1]);
    __builtin_amdgcn_s_barrier();

    // ---- P7: read A[2,3]
#pragma unroll
    for (int ks = 0; ks < 4; ++ks) {
      afr[0][ks] = LDA(1, 2, ks);
      afr[1][ks] = LDA(1, 3, ks);
    }
    __builtin_amdgcn_s_barrier();
    mfma8(acc[2][0], acc[3][0], afr, bfr[0]);
    __builtin_amdgcn_s_barrier();

    // ---- P8: stage t3.A0+A1 -> dbuf1; GATE t2 all landed
    if (more) {
      STAGE_A(0, t3, 1);
      STAGE_A(1, t3, 1);
      asm volatile("s_waitcnt vmcnt(4)" ::: "memory");
    } else {
      asm volatile("s_waitcnt vmcnt(0)" ::: "memory");
    }
    __builtin_amdgcn_s_barrier();
    mfma8(acc[2][1], acc[3][1], afr, bfr[1]);
    __builtin_amdgcn_s_barrier();
  }

#undef STAGE_A
#undef STAGE_B
#undef LDA
#undef LDB

  // epilogue: gated silu. BT rows n0+wn*64+{0..31}=w1 cols, {32..63}=w3 cols.
  const int ccol = (n0 >> 1) + wn * 32 + l31;
  const int rbase = m0 + wm * 128 + 4 * half;
#pragma unroll
  for (int mt = 0; mt < 4; ++mt)
#pragma unroll
    for (int reg = 0; reg < 16; ++reg) {
      int rr = rbase + mt * 32 + (reg & 3) + 8 * (reg >> 2);
      float a1v = acc[mt][0][reg];
      float a3v = acc[mt][1][reg];
      float f = a1v / (1.f + __expf(-a1v)) * a3v;
      F[(size_t)rr * 4096 + ccol] = f2bf(f);
    }
}

// ---------------------------------------------------------------------------
// Split-K GEMM, 128x128 tile, BK=64, K-window by blockIdx.z.
// ATOMIC=false: write f32 partials (wo). ATOMIC=true: atomicAdd into a
// residual-prefilled f32 output (w2) — replaces 64 MB partials + the 80 MB
// reduce4 pass with ~32 MB fire-and-forget atomic adds.
// ---------------------------------------------------------------------------
struct PtrPair { float* p0; float* p1; };

template <bool ATOMIC>
__device__ __forceinline__ void gemm_sk_body(
    const unsigned short* __restrict__ A, int lda,
    const unsigned short* __restrict__ BT,
    float* __restrict__ C, int Kc, int Ktot, int N, int kb) {
  __shared__ unsigned short As[128 * 64];
  __shared__ unsigned short Bs[128 * 64];
  const int t = threadIdx.x;
  const int lane = t & 63;
  const int w = t >> 6;
  const int qr = (w >> 1) * 64, qc = (w & 1) * 64;
  const int l31 = lane & 31, half = lane >> 5;
  const int m0 = blockIdx.y * 128, n0 = blockIdx.x * 128;

  f32x16 acc[2][2] = {};

  int srow[4], scol[4];
#pragma unroll
  for (int p = 0; p < 4; ++p) {
    int off = p * 2048 + t * 8;
    int r = off >> 6;
    srow[p] = r;
    scol[p] = ((((off >> 3) & 7) ^ (r & 7) ^ ((r >> 3) & 3))) * 8;
  }
  const int gsw = (l31 & 7) ^ (l31 >> 3);

  for (int k0 = kb; k0 < kb + Kc; k0 += 64) {
    __syncthreads();
#pragma unroll
    for (int p = 0; p < 4; ++p) {
      int off = p * 2048 + t * 8;
      async16(A + (size_t)(m0 + srow[p]) * lda + (k0 + scol[p]), &As[off]);
      async16(BT + (size_t)(n0 + srow[p]) * Ktot + (k0 + scol[p]), &Bs[off]);
    }
    __syncthreads();
#pragma unroll
    for (int ks = 0; ks < 4; ++ks) {
      const int ch = ((ks * 2 + half) ^ gsw) * 8;
      bf16x8 a0 = *(const bf16x8*)&As[(qr + l31) * 64 + ch];
      bf16x8 a1 = *(const bf16x8*)&As[(qr + 32 + l31) * 64 + ch];
      bf16x8 b0 = *(const bf16x8*)&Bs[(qc + l31) * 64 + ch];
      bf16x8 b1 = *(const bf16x8*)&Bs[(qc + 32 + l31) * 64 + ch];
      acc[0][0] = __builtin_amdgcn_mfma_f32_32x32x16_bf16(a0, b0, acc[0][0], 0, 0, 0);
      acc[0][1] = __builtin_amdgcn_mfma_f32_32x32x16_bf16(a0, b1, acc[0][1], 0, 0, 0);
      acc[1][0] = __builtin_amdgcn_mfma_f32_32x32x16_bf16(a1, b0, acc[1][0], 0, 0, 0);
      acc[1][1] = __builtin_amdgcn_mfma_f32_32x32x16_bf16(a1, b1, acc[1][1], 0, 0, 0);
    }
  }

#pragma unroll
  for (int rt = 0; rt < 2; ++rt)
#pragma unroll
    for (int ct = 0; ct < 2; ++ct)
#pragma unroll
      for (int reg = 0; reg < 16; ++reg) {
        int rr = m0 + qr + rt * 32 + (reg & 3) + 8 * (reg >> 2) + 4 * half;
        int cc = n0 + qc + ct * 32 + l31;
        if constexpr (ATOMIC)
          atomicAdd(&C[(size_t)rr * N + cc], acc[rt][ct][reg]);
        else
          C[(size_t)rr * N + cc] = acc[rt][ct][reg];
      }
}

__global__ __launch_bounds__(256) void gemm_bt_sk2(
    const unsigned short* __restrict__ A, int lda,
    const unsigned short* __restrict__ BT,
    PtrPair parts, int Kc, int Ktot, int N) {
  float* C = blockIdx.z ? parts.p1 : parts.p0;
  gemm_sk_body<false>(A, lda, BT, C, Kc, Ktot, N, blockIdx.z * Kc);
}

__global__ __launch_bounds__(256) void gemm_bt_sk4a(
    const unsigned short* __restrict__ A, int lda,
    const unsigned short* __restrict__ BT,
    float* __restrict__ Out, int Kc, int Ktot, int N) {
  gemm_sk_body<true>(A, lda, BT, Out, Kc, Ktot, N, blockIdx.z * Kc);
}

// ---------------------------------------------------------------------------
// reduce_norm_k: one row per block. h = p0+p1+resid; write h -> Out (f32,
// serves as the residual base that gemm_bt_sk4a atomically accumulates into);
// rmsnorm(h)*W -> Hin (bf16).
// ---------------------------------------------------------------------------
__global__ __launch_bounds__(256) void reduce_norm_k(
    const float4* __restrict__ P0, const float4* __restrict__ P1,
    const float4* __restrict__ R, float4* __restrict__ Out,
    const float* __restrict__ W, unsigned short* __restrict__ Hin) {
  const int row = blockIdx.x;
  const int t = threadIdx.x;
  const int lane = t & 63, w = t >> 6;
  const int i = row * 256 + t;
  float4 a = P0[i], b = P1[i], r = R[i];
  float4 h;
  h.x = a.x + b.x + r.x;
  h.y = a.y + b.y + r.y;
  h.z = a.z + b.z + r.z;
  h.w = a.w + b.w + r.w;
  Out[i] = h;
  float s = h.x * h.x + h.y * h.y + h.z * h.z + h.w * h.w;
#pragma unroll
  for (int m = 1; m < 64; m <<= 1) s += __shfl_xor(s, m, 64);
  __shared__ float red[4];
  if (lane == 0) red[w] = s;
  __syncthreads();
  float tot = red[0] + red[1] + red[2] + red[3];
  float inv = rsqrtf(tot * (1.0f / DMODEL) + 1e-6f);
  ushort4 o;
  o.x = f2bf(h.x * inv * W[t * 4 + 0]);
  o.y = f2bf(h.y * inv * W[t * 4 + 1]);
  o.z = f2bf(h.z * inv * W[t * 4 + 2]);
  o.w = f2bf(h.w * inv * W[t * 4 + 3]);
  *(ushort4*)(Hin + (size_t)row * DMODEL + t * 4) = o;
}

// ---------------------------------------------------------------------------
// Flash attention, swapped-QK^T 32x32 structure, no-max softmax, split-S.
// ---------------------------------------------------------------------------
__global__ __launch_bounds__(256) void attn_k(
    const unsigned short* __restrict__ QKV,
    const unsigned short* __restrict__ VtG,
    float* __restrict__ O0, float* __restrict__ O1,
    float* __restrict__ L) {
  const int h = blockIdx.y;
  const int qb = blockIdx.x;          // 0..15
  const int z = blockIdx.z;           // 0..1
  const int t = threadIdx.x;
  const int lane = t & 63;
  const int l31 = lane & 31, half = lane >> 5;
  const int w = t >> 6;               // wave 0..3
  const int q0 = qb * 128 + w * 32;
  const int kbase = z * 1024;
  const int gsw = (l31 & 7) ^ (l31 >> 3);

  __shared__ unsigned short Kt[2][64 * 64];
  __shared__ unsigned short Vt[2][64 * 64];

  const unsigned short* Kp = QKV + 1024 + h * 64;     // K columns of this head
  const unsigned short* Vg = VtG + (size_t)h * 64 * 2048;

  // Q fragments: lane holds Q[q0 + l31][ks*16 + half*8 .. +7]
  bf16x8 qf[4];
#pragma unroll
  for (int ks = 0; ks < 4; ++ks)
    qf[ks] = *(const bf16x8*)(QKV + (size_t)(q0 + l31) * 3072 + h * 64 + ks * 16 + half * 8);

  // prologue: stage tile 0 into buf 0
#pragma unroll
  for (int p = 0; p < 2; ++p) {
    int off = p * 2048 + t * 8;
    int r = off >> 6;
    int sc8 = (((off >> 3) & 7) ^ (r & 7) ^ ((r >> 3) & 3)) * 8;
    async16(Kp + (size_t)(kbase + r) * 3072 + sc8, &Kt[0][off]);
    async16(Vg + (size_t)r * 2048 + kbase + sc8, &Vt[0][off]);
  }
  asm volatile("s_waitcnt vmcnt(0)" ::: "memory");
  __syncthreads();

  f32x16 oacc[2] = {};
  float l_r = 0.f;

#pragma unroll 1
  for (int kt = 0; kt < 16; ++kt) {
    const int cur = kt & 1;
    // stage next tile into the other buffer (drained by end-of-iter barrier)
    if (kt + 1 < 16) {
      int kb2 = kbase + (kt + 1) * 64;
#pragma unroll
      for (int p = 0; p < 2; ++p) {
        int off = p * 2048 + t * 8;
        int r = off >> 6;
        int sc8 = (((off >> 3) & 7) ^ (r & 7) ^ ((r >> 3) & 3)) * 8;
        async16(Kp + (size_t)(kb2 + r) * 3072 + sc8, &Kt[cur ^ 1][off]);
        async16(Vg + (size_t)r * 2048 + kb2 + sc8, &Vt[cur ^ 1][off]);
      }
    }

    // QK^T (swapped): st[kblk] reg r = S[k = kblk*32+(r&3)+8*(r>>2)+4*half][q=l31]
    f32x16 st[2] = {};
#pragma unroll
    for (int ks = 0; ks < 4; ++ks) {
      const int ch = ((2 * ks + half) ^ gsw) * 8;
      bf16x8 k0 = *(const bf16x8*)&Kt[cur][l31 * 64 + ch];
      bf16x8 k1 = *(const bf16x8*)&Kt[cur][(32 + l31) * 64 + ch];
      st[0] = __builtin_amdgcn_mfma_f32_32x32x16_bf16(k0, qf[ks], st[0], 0, 0, 0);
      st[1] = __builtin_amdgcn_mfma_f32_32x32x16_bf16(k1, qf[ks], st[1], 0, 0, 0);
    }

    // no-max softmax: exp + per-lane partial row sum (partner half added at end)
    float psum = 0.f;
#pragma unroll
    for (int b = 0; b < 2; ++b)
#pragma unroll
      for (int r = 0; r < 16; ++r) {
        float e = __expf(st[b][r]);
        st[b][r] = e;
        psum += e;
      }
    l_r += psum;

    // pack P to bf16 pairs: group j=b*4+m covers k = 8j + 4*half + {0..3}
    unsigned int pklo[8], pkhi[8];
#pragma unroll
    for (int b = 0; b < 2; ++b)
#pragma unroll
      for (int m = 0; m < 4; ++m) {
        pklo[b * 4 + m] = pk_trunc(st[b][4 * m + 0], st[b][4 * m + 1]);
        pkhi[b * 4 + m] = pk_trunc(st[b][4 * m + 2], st[b][4 * m + 3]);
      }

    // PV: A-fragment lane supplies P[q=l31][16ks + 8*half + e] (group j*=2ks+half)
#pragma unroll
    for (int ks = 0; ks < 4; ++ks) {
      unsigned int keep_lo = half ? pklo[2 * ks + 1] : pklo[2 * ks];
      unsigned int keep_hi = half ? pkhi[2 * ks + 1] : pkhi[2 * ks];
      unsigned int pass_lo = half ? pklo[2 * ks] : pklo[2 * ks + 1];
      unsigned int pass_hi = half ? pkhi[2 * ks] : pkhi[2 * ks + 1];
      unsigned int olo = (unsigned int)__shfl_xor((int)pass_lo, 32, 64);
      unsigned int ohi = (unsigned int)__shfl_xor((int)pass_hi, 32, 64);
      unsigned int w0 = half ? olo : keep_lo;   // k offsets 0,1
      unsigned int w1 = half ? ohi : keep_hi;   // 2,3
      unsigned int w2 = half ? keep_lo : olo;   // 4,5
      unsigned int w3 = half ? keep_hi : ohi;   // 6,7
      bf16x8 af = mk_bf16x8(w0, w1, w2, w3);
      const int ch = ((2 * ks + half) ^ gsw) * 8;
      bf16x8 v0 = *(const bf16x8*)&Vt[cur][l31 * 64 + ch];
      bf16x8 v1 = *(const bf16x8*)&Vt[cur][(32 + l31) * 64 + ch];
      oacc[0] = __builtin_amdgcn_mfma_f32_32x32x16_bf16(af, v0, oacc[0], 0, 0, 0);
      oacc[1] = __builtin_amdgcn_mfma_f32_32x32x16_bf16(af, v1, oacc[1], 0, 0, 0);
    }

    __syncthreads();   // drains vmcnt+lgkm: next tile landed, reads done
  }

  float lt = l_r + __shfl_xor(l_r, 32, 64);
  float* Op = z ? O1 : O0;
#pragma unroll
  for (int db = 0; db < 2; ++db)
#pragma unroll
    for (int reg = 0; reg < 16; ++reg) {
      int q = (reg & 3) + 8 * (reg >> 2) + 4 * half;
      Op[(size_t)(q0 + q) * DMODEL + h * 64 + db * 32 + l31] = oacc[db][reg];
    }
  if (half == 0)
    L[(size_t)(h * 2 + z) * S_LEN + q0 + l31] = lt;
}

// Attn = bf16((O0+O1) / (l0+l1)); layout [s][h*64+d]
__global__ __launch_bounds__(256) void attn_combine_k(
    const float4* __restrict__ O0, const float4* __restrict__ O1,
    const float* __restrict__ L, unsigned short* __restrict__ Attn) {
  int i = blockIdx.x * 256 + threadIdx.x;
  int e0 = i * 4;
  int s = e0 >> 10;
  int c = e0 & 1023;
  int h = c >> 6;
  float la = L[(size_t)(h * 2) * S_LEN + s];
  float lb = L[(size_t)(h * 2 + 1) * S_LEN + s];
  float inv = 1.f / (la + lb);
  float4 a = O0[i], b = O1[i];
  ushort4 r;
  r.x = f2bf((a.x + b.x) * inv);
  r.y = f2bf((a.y + b.y) * inv);
  r.z = f2bf((a.z + b.z) * inv);
  r.w = f2bf((a.w + b.w) * inv);
  *(ushort4*)(Attn + e0) = r;
}

// ---------------------------------------------------------------------------
// Launch — 9 dispatches (was 10; reduce4 replaced by atomic split-K)
// ---------------------------------------------------------------------------
extern "C" void kernel_launch(void* const* d_in, const int* in_sizes, int n_in,
                              void* d_out, int out_size, void* d_ws, size_t ws_size,
                              hipStream_t stream) {
  (void)in_sizes; (void)n_in; (void)out_size; (void)ws_size;
  const float* x    = (const float*)d_in[0];
  const float* fcos = (const float*)d_in[1];
  const float* fsin = (const float*)d_in[2];
  const float* wq   = (const float*)d_in[3];
  const float* wk   = (const float*)d_in[4];
  const float* wv   = (const float*)d_in[5];
  const float* wo   = (const float*)d_in[6];
  const float* w1   = (const float*)d_in[7];
  const float* w2   = (const float*)d_in[8];
  const float* w3   = (const float*)d_in[9];
  const float* anw  = (const float*)d_in[10];
  const float* fnw  = (const float*)d_in[11];
  float* out = (float*)d_out;
  char* ws = (char*)d_ws;

  // ---- workspace layout (bytes), total 71,303,168 ----
  unsigned short* WqkvT = (unsigned short*)(ws + 0);
  unsigned short* VtG   = (unsigned short*)(ws + 0);
  float*          Lbuf  = (float*)(ws + 4194304);
  unsigned short* WoT   = (unsigned short*)(ws + 6291456);
  unsigned short* QKV   = (unsigned short*)(ws + 8388608);
  unsigned short* Attn  = (unsigned short*)(ws + 20971520);
  float* Oa             = (float*)(ws + 25165824);
  float* Ob             = (float*)(ws + 37748736);
  float* P0a            = (float*)(ws + 8388608);
  float* P1a            = (float*)(ws + 25165824);
  unsigned short* F     = (unsigned short*)(ws + 0);
  unsigned short* Hin   = (unsigned short*)(ws + 33554432);
  unsigned short* W13I  = (unsigned short*)(ws + 46137344);
  unsigned short* W2T   = (unsigned short*)(ws + 62914560);

  // 1. fused weight transposes + rmsnorm(x)->Hin
  prep_k<<<6144, 256, 0, stream>>>(PrepArgs{
      wq, wk, wv, wo, w1, w3, w2, x, anw,
      WqkvT, WoT, W13I, W2T, Hin});

  // attention branch
  gemm_bt<0><<<dim3(24, 16), 256, 0, stream>>>(Hin, 1024, WqkvT, QKV, 1024, 3072);
  rope_vtrans_k<<<4608, 256, 0, stream>>>(QKV, fcos, fsin, VtG);
  attn_k<<<dim3(16, 16, 2), 256, 0, stream>>>(QKV, VtG, Oa, Ob, Lbuf);
  attn_combine_k<<<2048, 256, 0, stream>>>((const float4*)Oa, (const float4*)Ob, Lbuf, Attn);
  gemm_bt_sk2<<<dim3(8, 16, 2), 256, 0, stream>>>(Attn, 1024, WoT, PtrPair{P0a, P1a}, 512, 1024, 1024);
  // writes residual h -> out (f32 base for the atomic FFN-down accumulation)
  reduce_norm_k<<<2048, 256, 0, stream>>>((const float4*)P0a, (const float4*)P1a,
                                          (const float4*)x, (float4*)out, fnw, Hin);

  // ffn branch
  gemm256_silu<<<dim3(256), 512, 0, stream>>>(Hin, W13I, F);
  gemm_bt_sk4a<<<dim3(8, 16, 4), 256, 0, stream>>>(F, 4096, W2T, out, 1024, 4096, 1024);
}

// Round 10
// 281.087 us; speedup vs baseline: 1.0625x; 1.0625x over previous
//
#include <hip/hip_runtime.h>
#include <stdint.h>
#include <stddef.h>

// ---------------------------------------------------------------------------
// Types / helpers
// ---------------------------------------------------------------------------
using bf16x8 = __attribute__((ext_vector_type(8))) __bf16;
using f32x4  = __attribute__((ext_vector_type(4))) float;
using f32x16 = __attribute__((ext_vector_type(16))) float;

__device__ __forceinline__ float bf2f(unsigned short u) {
  union { unsigned int i; float f; } v; v.i = ((unsigned int)u) << 16; return v.f;
}
__device__ __forceinline__ unsigned short f2bf(float f) {
  union { float f; unsigned int i; } v; v.f = f;
  unsigned int r = v.i + 0x7fffu + ((v.i >> 16) & 1u);   // RNE
  return (unsigned short)(r >> 16);
}
__device__ __forceinline__ unsigned short f2bf_trunc(float f) {
  union { float f; unsigned int i; } v; v.f = f;
  return (unsigned short)(v.i >> 16);
}
// pack two f32 -> u32 of two truncated bf16 (lo = a, hi = b)
__device__ __forceinline__ unsigned int pk_trunc(float a, float b) {
  union { float f; unsigned int i; } x, y; x.f = a; y.f = b;
  return (x.i >> 16) | (y.i & 0xffff0000u);
}
__device__ __forceinline__ bf16x8 mk_bf16x8(unsigned int a, unsigned int b,
                                            unsigned int c, unsigned int d) {
  union { unsigned int u[4]; bf16x8 v; } x;
  x.u[0] = a; x.u[1] = b; x.u[2] = c; x.u[3] = d; return x.v;
}
// async global->LDS, 16 B/lane; LDS dest must be wave-uniform base + lane*16.
__device__ __forceinline__ void async16(const void* g, void* l) {
  __builtin_amdgcn_global_load_lds(
      (const __attribute__((address_space(1))) unsigned int*)g,
      (__attribute__((address_space(3))) unsigned int*)l, 16, 0, 0);
}

#define S_LEN 2048
#define DMODEL 1024
#define NHEAD 16
#define DHEAD 64
#define DFFN 4096

// ---------------------------------------------------------------------------
// prep_k: fused weight transposes (64x64 vectorized tiles) + rmsnorm(x)->Hin.
// ---------------------------------------------------------------------------
struct PrepArgs {
  const float *wq, *wk, *wv, *wo, *w1, *w3, *w2, *x, *anw;
  unsigned short *WqkvT, *WoT, *W13I, *W2T, *Hin;
};
__global__ __launch_bounds__(256) void prep_k(PrepArgs a) {
  __shared__ unsigned short tile[64][66];
  __shared__ float red[4];
  const int bid = blockIdx.x;
  const int t = threadIdx.x;

  if (bid < 4096) {
    const float* in;
    unsigned short* out;
    int src_ld, dst_ld, bx, by;
    bool w13 = false;
    int rb = 0;
    if (bid < 1024) {
      int z = bid >> 8, rem = bid & 255;
      bx = rem & 15; by = rem >> 4;
      in = z == 0 ? a.wq : z == 1 ? a.wk : z == 2 ? a.wv : a.wo;
      out = z == 0 ? a.WqkvT : z == 1 ? a.WqkvT + 1048576 : z == 2 ? a.WqkvT + 2097152 : a.WoT;
      src_ld = 1024; dst_ld = 1024;
    } else if (bid < 3072) {
      int r = bid - 1024;
      int z = r >> 10, rem = r & 1023;
      bx = rem & 63; by = rem >> 6;
      in = z ? a.w3 : a.w1;
      out = a.W13I;
      src_ld = 4096; dst_ld = 1024;
      w13 = true; rb = z * 32;
    } else {
      int r = bid - 3072;
      bx = r & 15; by = r >> 4;
      in = a.w2; out = a.W2T;
      src_ld = 1024; dst_ld = 4096;
    }
    const int br = by * 64, bc = bx * 64;
    const int rr = t >> 4, c4 = (t & 15) * 4;
#pragma unroll
    for (int i = 0; i < 4; ++i) {
      int row = rr + i * 16;
      float4 v = *(const float4*)&in[(size_t)(br + row) * src_ld + bc + c4];
      tile[row][c4 + 0] = f2bf(v.x);
      tile[row][c4 + 1] = f2bf(v.y);
      tile[row][c4 + 2] = f2bf(v.z);
      tile[row][c4 + 3] = f2bf(v.w);
    }
    __syncthreads();
    const int x = t >> 2, y16 = (t & 3) * 16;
    int dest = bc + x;
    if (w13) dest = (bc >> 5) * 64 + (x >> 5) * 64 + rb + (x & 31);
#pragma unroll
    for (int i = 0; i < 2; ++i) {
      int y0 = y16 + i * 8;
      ushort4 o0, o1;
      o0.x = tile[y0 + 0][x]; o0.y = tile[y0 + 1][x];
      o0.z = tile[y0 + 2][x]; o0.w = tile[y0 + 3][x];
      o1.x = tile[y0 + 4][x]; o1.y = tile[y0 + 5][x];
      o1.z = tile[y0 + 6][x]; o1.w = tile[y0 + 7][x];
      *(ushort4*)&out[(size_t)dest * dst_ld + br + y0] = o0;
      *(ushort4*)&out[(size_t)dest * dst_ld + br + y0 + 4] = o1;
    }
  } else {
    // rmsnorm row
    const int row = bid - 4096;
    const int lane = t & 63, w = t >> 6;
    const float* x = a.x + (size_t)row * DMODEL;
    float xs[4];
    float s = 0.f;
#pragma unroll
    for (int i = 0; i < 4; ++i) {
      xs[i] = x[t * 4 + i];
      s += xs[i] * xs[i];
    }
#pragma unroll
    for (int m = 1; m < 64; m <<= 1) s += __shfl_xor(s, m, 64);
    if (lane == 0) red[w] = s;
    __syncthreads();
    float tot = red[0] + red[1] + red[2] + red[3];
    float inv = rsqrtf(tot * (1.0f / DMODEL) + 1e-6f);
#pragma unroll
    for (int i = 0; i < 4; ++i)
      a.Hin[(size_t)row * DMODEL + t * 4 + i] = f2bf(xs[i] * inv * a.anw[t * 4 + i]);
  }
}

// ---------------------------------------------------------------------------
// rope_vtrans_k: fused RoPE (bid<1024, vectorized: 4 pairs/thread, ushort4x2
// loads/stores + float4 cos/sin) + V-transpose (bid>=1024).
// Arithmetic per pair identical to the scalar version (bit-exact output).
// ---------------------------------------------------------------------------
__global__ __launch_bounds__(256) void rope_vtrans_k(
    unsigned short* __restrict__ QKV,
    const float* __restrict__ cosp,
    const float* __restrict__ sinp,
    unsigned short* __restrict__ VtG) {
  __shared__ unsigned short tile[64][66];
  const int bid = blockIdx.x;
  const int t = threadIdx.x;
  if (bid < 1024) {
    int idx = bid * 256 + t;          // 262144 threads: 2048 s x 16 h x 8 g
    int s = idx >> 7;
    int rem = idx & 127;
    int h = rem >> 3;
    int g = rem & 7;
    float4 cv = *(const float4*)&cosp[s * 32 + g * 4];
    float4 sv = *(const float4*)&sinp[s * 32 + g * 4];
    size_t off = (size_t)s * 3072 + h * 64 + g * 8;
    ushort4 a0 = *(ushort4*)&QKV[off];
    ushort4 a1 = *(ushort4*)&QKV[off + 4];
    ushort4 b0 = *(ushort4*)&QKV[off + 1024];
    ushort4 b1 = *(ushort4*)&QKV[off + 1028];
    float e, o;
    // Q pairs
    e = bf2f(a0.x); o = bf2f(a0.y);
    a0.x = f2bf(e * cv.x - o * sv.x); a0.y = f2bf(e * sv.x + o * cv.x);
    e = bf2f(a0.z); o = bf2f(a0.w);
    a0.z = f2bf(e * cv.y - o * sv.y); a0.w = f2bf(e * sv.y + o * cv.y);
    e = bf2f(a1.x); o = bf2f(a1.y);
    a1.x = f2bf(e * cv.z - o * sv.z); a1.y = f2bf(e * sv.z + o * cv.z);
    e = bf2f(a1.z); o = bf2f(a1.w);
    a1.z = f2bf(e * cv.w - o * sv.w); a1.w = f2bf(e * sv.w + o * cv.w);
    // K pairs, pre-scaled 0.125 (exact in bf16)
    e = bf2f(b0.x); o = bf2f(b0.y);
    b0.x = f2bf((e * cv.x - o * sv.x) * 0.125f);
    b0.y = f2bf((e * sv.x + o * cv.x) * 0.125f);
    e = bf2f(b0.z); o = bf2f(b0.w);
    b0.z = f2bf((e * cv.y - o * sv.y) * 0.125f);
    b0.w = f2bf((e * sv.y + o * cv.y) * 0.125f);
    e = bf2f(b1.x); o = bf2f(b1.y);
    b1.x = f2bf((e * cv.z - o * sv.z) * 0.125f);
    b1.y = f2bf((e * sv.z + o * cv.z) * 0.125f);
    e = bf2f(b1.z); o = bf2f(b1.w);
    b1.z = f2bf((e * cv.w - o * sv.w) * 0.125f);
    b1.w = f2bf((e * sv.w + o * cv.w) * 0.125f);
    *(ushort4*)&QKV[off] = a0;
    *(ushort4*)&QKV[off + 4] = a1;
    *(ushort4*)&QKV[off + 1024] = b0;
    *(ushort4*)&QKV[off + 1028] = b1;
  } else {
    int r = bid - 1024;
    const int bx = r & 15, by = r >> 4;
    const int br = by * 64, bc = bx * 64;
    const int rr = t >> 4, c4 = (t & 15) * 4;
#pragma unroll
    for (int i = 0; i < 4; ++i) {
      int row = rr + i * 16;
      ushort4 v = *(const ushort4*)&QKV[(size_t)(br + row) * 3072 + 2048 + bc + c4];
      tile[row][c4 + 0] = v.x;
      tile[row][c4 + 1] = v.y;
      tile[row][c4 + 2] = v.z;
      tile[row][c4 + 3] = v.w;
    }
    __syncthreads();
    const int x = t >> 2, y16 = (t & 3) * 16;
#pragma unroll
    for (int i = 0; i < 2; ++i) {
      int y0 = y16 + i * 8;
      ushort4 o0, o1;
      o0.x = tile[y0 + 0][x]; o0.y = tile[y0 + 1][x];
      o0.z = tile[y0 + 2][x]; o0.w = tile[y0 + 3][x];
      o1.x = tile[y0 + 4][x]; o1.y = tile[y0 + 5][x];
      o1.z = tile[y0 + 6][x]; o1.w = tile[y0 + 7][x];
      *(ushort4*)&VtG[(size_t)(bc + x) * 2048 + br + y0] = o0;
      *(ushort4*)&VtG[(size_t)(bc + x) * 2048 + br + y0 + 4] = o1;
    }
  }
}

// ---------------------------------------------------------------------------
// GEMM C = A[M,K](bf16) @ BT[N,K](bf16)^T, f32 accum.
// 128x128 tile, BK=64, mfma_32x32x16, async16 staging.
// ---------------------------------------------------------------------------
template <int MODE>
__global__ __launch_bounds__(256) void gemm_bt(
    const unsigned short* __restrict__ A, int lda,
    const unsigned short* __restrict__ BT,
    void* __restrict__ Cout,
    int K, int N) {
  __shared__ unsigned short As[128 * 64];
  __shared__ unsigned short Bs[128 * 64];
  const int t = threadIdx.x;
  const int lane = t & 63;
  const int w = t >> 6;
  const int qr = (w >> 1) * 64, qc = (w & 1) * 64;
  const int l31 = lane & 31, half = lane >> 5;
  const int m0 = blockIdx.y * 128, n0 = blockIdx.x * 128;

  f32x16 acc[2][2] = {};

  int srow[4], scol[4];
#pragma unroll
  for (int p = 0; p < 4; ++p) {
    int off = p * 2048 + t * 8;
    int r = off >> 6;
    srow[p] = r;
    scol[p] = ((((off >> 3) & 7) ^ (r & 7) ^ ((r >> 3) & 3))) * 8;
  }
  const int gsw = (l31 & 7) ^ (l31 >> 3);

  for (int k0 = 0; k0 < K; k0 += 64) {
    __syncthreads();
#pragma unroll
    for (int p = 0; p < 4; ++p) {
      int off = p * 2048 + t * 8;
      async16(A + (size_t)(m0 + srow[p]) * lda + (k0 + scol[p]), &As[off]);
      async16(BT + (size_t)(n0 + srow[p]) * K + (k0 + scol[p]), &Bs[off]);
    }
    __syncthreads();
#pragma unroll
    for (int ks = 0; ks < 4; ++ks) {
      const int ch = ((ks * 2 + half) ^ gsw) * 8;
      bf16x8 a0 = *(const bf16x8*)&As[(qr + l31) * 64 + ch];
      bf16x8 a1 = *(const bf16x8*)&As[(qr + 32 + l31) * 64 + ch];
      bf16x8 b0 = *(const bf16x8*)&Bs[(qc + l31) * 64 + ch];
      bf16x8 b1 = *(const bf16x8*)&Bs[(qc + 32 + l31) * 64 + ch];
      acc[0][0] = __builtin_amdgcn_mfma_f32_32x32x16_bf16(a0, b0, acc[0][0], 0, 0, 0);
      acc[0][1] = __builtin_amdgcn_mfma_f32_32x32x16_bf16(a0, b1, acc[0][1], 0, 0, 0);
      acc[1][0] = __builtin_amdgcn_mfma_f32_32x32x16_bf16(a1, b0, acc[1][0], 0, 0, 0);
      acc[1][1] = __builtin_amdgcn_mfma_f32_32x32x16_bf16(a1, b1, acc[1][1], 0, 0, 0);
    }
  }

  // C/D layout: col = lane&31, row = (reg&3) + 8*(reg>>2) + 4*half
  {
    unsigned short* C = (unsigned short*)Cout;
#pragma unroll
    for (int rt = 0; rt < 2; ++rt)
#pragma unroll
      for (int ct = 0; ct < 2; ++ct)
#pragma unroll
        for (int reg = 0; reg < 16; ++reg) {
          int rr = m0 + qr + rt * 32 + (reg & 3) + 8 * (reg >> 2) + 4 * half;
          int cc = n0 + qc + ct * 32 + l31;
          C[(size_t)rr * N + cc] = f2bf(acc[rt][ct][reg]);
        }
  }
}

// ---------------------------------------------------------------------------
// FFN w1/w3 gated GEMM, 256x256 tile, BK=64, 8 waves (2M x 4N), 8-phase.
// The R2 structure + old row&7 swizzle. (Per-session clock-state varies
// absolute dispatch times 1.4x; only e2e / within-session deltas count.)
// ---------------------------------------------------------------------------
__device__ __forceinline__ void mfma8(f32x16& c0, f32x16& c1,
                                      const bf16x8 (&a)[2][4],
                                      const bf16x8 (&b)[4]) {
  __builtin_amdgcn_s_setprio(1);
#pragma unroll
  for (int ks = 0; ks < 4; ++ks) {
    c0 = __builtin_amdgcn_mfma_f32_32x32x16_bf16(a[0][ks], b[ks], c0, 0, 0, 0);
    c1 = __builtin_amdgcn_mfma_f32_32x32x16_bf16(a[1][ks], b[ks], c1, 0, 0, 0);
  }
  __builtin_amdgcn_s_setprio(0);
}

__global__ __launch_bounds__(512, 2) void gemm256_silu(
    const unsigned short* __restrict__ A,   // Hin [2048][1024]
    const unsigned short* __restrict__ BT,  // W13I [8192][1024]
    unsigned short* __restrict__ F) {       // out  [2048][4096]
  __shared__ unsigned short lds[65536];     // 128 KiB: [d][As 16384 | Bs 16384]
  const int t = threadIdx.x;
  const int l = t & 63, l31 = l & 31, half = l >> 5;
  const int w = t >> 6;
  const int wm = w >> 2, wn = w & 3;

  const int orig = blockIdx.x;
  const int bx = (orig & 7) * 4 + ((orig >> 3) & 3);
  const int by = orig >> 5;
  const int m0 = by * 256, n0 = bx * 256;

  const int rA = t >> 3;                              // row within 64-row block
  const int sc = ((t & 7) ^ ((t >> 3) & 7)) * 8;      // swizzled k-chunk col
  const int lo = t * 8;                               // lds elems within 4096

#define STAGE_A(h, tile, d)                                                    \
  { async16(A + (size_t)(m0 + (h) * 128 + rA) * 1024 + (tile) * 64 + sc,       \
            &lds[(d) * 32768 + (h) * 8192 + lo]);                              \
    async16(A + (size_t)(m0 + (h) * 128 + 64 + rA) * 1024 + (tile) * 64 + sc,  \
            &lds[(d) * 32768 + (h) * 8192 + 4096 + lo]); }
#define STAGE_B(h, tile, d)                                                    \
  { async16(BT + (size_t)(n0 + (h) * 128 + rA) * 1024 + (tile) * 64 + sc,      \
            &lds[(d) * 32768 + 16384 + (h) * 8192 + lo]);                      \
    async16(BT + (size_t)(n0 + (h) * 128 + 64 + rA) * 1024 + (tile) * 64 + sc, \
            &lds[(d) * 32768 + 16384 + (h) * 8192 + 4096 + lo]); }

  const int arow = wm * 128 + l31;
  const int brow = wn * 64 + l31;
  int kc[4];
#pragma unroll
  for (int ks = 0; ks < 4; ++ks) kc[ks] = ((ks * 2 + half) ^ (l31 & 7)) * 8;

#define LDA(d, mt, ks) (*(const bf16x8*)&lds[(d) * 32768 + (arow + (mt) * 32) * 64 + kc[ks]])
#define LDB(d, nt, ks) (*(const bf16x8*)&lds[(d) * 32768 + 16384 + (brow + (nt) * 32) * 64 + kc[ks]])

  f32x16 acc[4][2] = {};
  bf16x8 afr[2][4], bfr[2][4];

  // prologue: tile0 all 4 halves -> dbuf0; tile1.A0+A1 -> dbuf1
  STAGE_A(0, 0, 0); STAGE_A(1, 0, 0); STAGE_B(0, 0, 0); STAGE_B(1, 0, 0);
  STAGE_A(0, 1, 1); STAGE_A(1, 1, 1);
  asm volatile("s_waitcnt vmcnt(4)" ::: "memory");
  __builtin_amdgcn_s_barrier();

#pragma unroll 1
  for (int i = 0; i < 8; ++i) {
    const int t1 = 2 * i + 1, t2 = 2 * i + 2, t3 = 2 * i + 3;
    const bool more = i < 7;

    // ---- P1: read dbuf0 A[0,1],B[0]; stage t1.B0 -> dbuf1
#pragma unroll
    for (int ks = 0; ks < 4; ++ks) {
      afr[0][ks] = LDA(0, 0, ks);
      afr[1][ks] = LDA(0, 1, ks);
      bfr[0][ks] = LDB(0, 0, ks);
    }
    STAGE_B(0, t1, 1);
    __builtin_amdgcn_s_barrier();
    mfma8(acc[0][0], acc[1][0], afr, bfr[0]);
    __builtin_amdgcn_s_barrier();

    // ---- P2: read B[1]; stage t1.B1 -> dbuf1
#pragma unroll
    for (int ks = 0; ks < 4; ++ks) bfr[1][ks] = LDB(0, 1, ks);
    STAGE_B(1, t1, 1);
    __builtin_amdgcn_s_barrier();
    mfma8(acc[0][1], acc[1][1], afr, bfr[1]);
    __builtin_amdgcn_s_barrier();

    // ---- P3: read A[2,3]; stage t2.B0 -> dbuf0
#pragma unroll
    for (int ks = 0; ks < 4; ++ks) {
      afr[0][ks] = LDA(0, 2, ks);
      afr[1][ks] = LDA(0, 3, ks);
    }
    if (more) STAGE_B(0, t2, 0);
    __builtin_amdgcn_s_barrier();
    mfma8(acc[2][1], acc[3][1], afr, bfr[1]);
    __builtin_amdgcn_s_barrier();

    // ---- P4: stage t2.B1 + t2.A0 -> dbuf0; GATE t1.{A,B0}
    if (more) {
      STAGE_B(1, t2, 0);
      STAGE_A(0, t2, 0);
      asm volatile("s_waitcnt vmcnt(8)" ::: "memory");
    } else {
      asm volatile("s_waitcnt vmcnt(2)" ::: "memory");
    }
    __builtin_amdgcn_s_barrier();
    mfma8(acc[2][0], acc[3][0], afr, bfr[0]);   // bfr[0] live since P1
    __builtin_amdgcn_s_barrier();

    // ---- P5: read dbuf1 A[0,1],B[0]; stage t2.A1 -> dbuf0; GATE t1.B1
#pragma unroll
    for (int ks = 0; ks < 4; ++ks) {
      afr[0][ks] = LDA(1, 0, ks);
      afr[1][ks] = LDA(1, 1, ks);
      bfr[0][ks] = LDB(1, 0, ks);
    }
    if (more) {
      STAGE_A(1, t2, 0);
      asm volatile("s_waitcnt vmcnt(8)" ::: "memory");
    } else {
      asm volatile("s_waitcnt vmcnt(0)" ::: "memory");
    }
    __builtin_amdgcn_s_barrier();
    mfma8(acc[0][0], acc[1][0], afr, bfr[0]);
    __builtin_amdgcn_s_barrier();

    // ---- P6: read B[1]
#pragma unroll
    for (int ks = 0; ks < 4; ++ks) bfr[1][ks] = LDB(1, 1, ks);
    __builtin_amdgcn_s_barrier();
    mfma8(acc[0][1], acc[1][1], afr, bfr[1]);
    __builtin_amdgcn_s_barrier();

    // ---- P7: read A[2,3]
#pragma unroll
    for (int ks = 0; ks < 4; ++ks) {
      afr[0][ks] = LDA(1, 2, ks);
      afr[1][ks] = LDA(1, 3, ks);
    }
    __builtin_amdgcn_s_barrier();
    mfma8(acc[2][1], acc[3][1], afr, bfr[1]);
    __builtin_amdgcn_s_barrier();

    // ---- P8: stage t3.A0+A1 -> dbuf1; GATE t2 all landed
    if (more) {
      STAGE_A(0, t3, 1);
      STAGE_A(1, t3, 1);
      asm volatile("s_waitcnt vmcnt(4)" ::: "memory");
    } else {
      asm volatile("s_waitcnt vmcnt(0)" ::: "memory");
    }
    __builtin_amdgcn_s_barrier();
    mfma8(acc[2][0], acc[3][0], afr, bfr[0]);
    __builtin_amdgcn_s_barrier();
  }

#undef STAGE_A
#undef STAGE_B
#undef LDA
#undef LDB

  // epilogue: gated silu. BT rows n0+wn*64+{0..31}=w1 cols, {32..63}=w3 cols.
  const int ccol = (n0 >> 1) + wn * 32 + l31;
  const int rbase = m0 + wm * 128 + 4 * half;
#pragma unroll
  for (int mt = 0; mt < 4; ++mt)
#pragma unroll
    for (int reg = 0; reg < 16; ++reg) {
      int rr = rbase + mt * 32 + (reg & 3) + 8 * (reg >> 2);
      float a1v = acc[mt][0][reg];
      float a3v = acc[mt][1][reg];
      float f = a1v / (1.f + __expf(-a1v)) * a3v;
      F[(size_t)rr * 4096 + ccol] = f2bf(f);
    }
}

// ---------------------------------------------------------------------------
// Split-K GEMM, 128x128 tile, BK=64, K-window by blockIdx.z, f32 partials.
// Explicit partials + reduce pass ONLY — R9 proved per-element global
// atomicAdd executes as HBM RMW (cross-XCD coherence point): FETCH 69.7 MB,
// 2.2 TB/s, e2e +15 us. Do not re-introduce atomics here.
// ---------------------------------------------------------------------------
struct PtrPair { float* p0; float* p1; };
struct PtrQuad { float* p0; float* p1; float* p2; float* p3; };

__device__ __forceinline__ void gemm_sk_body(
    const unsigned short* __restrict__ A, int lda,
    const unsigned short* __restrict__ BT,
    float* __restrict__ C, int Kc, int Ktot, int N, int kb) {
  __shared__ unsigned short As[128 * 64];
  __shared__ unsigned short Bs[128 * 64];
  const int t = threadIdx.x;
  const int lane = t & 63;
  const int w = t >> 6;
  const int qr = (w >> 1) * 64, qc = (w & 1) * 64;
  const int l31 = lane & 31, half = lane >> 5;
  const int m0 = blockIdx.y * 128, n0 = blockIdx.x * 128;

  f32x16 acc[2][2] = {};

  int srow[4], scol[4];
#pragma unroll
  for (int p = 0; p < 4; ++p) {
    int off = p * 2048 + t * 8;
    int r = off >> 6;
    srow[p] = r;
    scol[p] = ((((off >> 3) & 7) ^ (r & 7) ^ ((r >> 3) & 3))) * 8;
  }
  const int gsw = (l31 & 7) ^ (l31 >> 3);

  for (int k0 = kb; k0 < kb + Kc; k0 += 64) {
    __syncthreads();
#pragma unroll
    for (int p = 0; p < 4; ++p) {
      int off = p * 2048 + t * 8;
      async16(A + (size_t)(m0 + srow[p]) * lda + (k0 + scol[p]), &As[off]);
      async16(BT + (size_t)(n0 + srow[p]) * Ktot + (k0 + scol[p]), &Bs[off]);
    }
    __syncthreads();
#pragma unroll
    for (int ks = 0; ks < 4; ++ks) {
      const int ch = ((ks * 2 + half) ^ gsw) * 8;
      bf16x8 a0 = *(const bf16x8*)&As[(qr + l31) * 64 + ch];
      bf16x8 a1 = *(const bf16x8*)&As[(qr + 32 + l31) * 64 + ch];
      bf16x8 b0 = *(const bf16x8*)&Bs[(qc + l31) * 64 + ch];
      bf16x8 b1 = *(const bf16x8*)&Bs[(qc + 32 + l31) * 64 + ch];
      acc[0][0] = __builtin_amdgcn_mfma_f32_32x32x16_bf16(a0, b0, acc[0][0], 0, 0, 0);
      acc[0][1] = __builtin_amdgcn_mfma_f32_32x32x16_bf16(a0, b1, acc[0][1], 0, 0, 0);
      acc[1][0] = __builtin_amdgcn_mfma_f32_32x32x16_bf16(a1, b0, acc[1][0], 0, 0, 0);
      acc[1][1] = __builtin_amdgcn_mfma_f32_32x32x16_bf16(a1, b1, acc[1][1], 0, 0, 0);
    }
  }

#pragma unroll
  for (int rt = 0; rt < 2; ++rt)
#pragma unroll
    for (int ct = 0; ct < 2; ++ct)
#pragma unroll
      for (int reg = 0; reg < 16; ++reg) {
        int rr = m0 + qr + rt * 32 + (reg & 3) + 8 * (reg >> 2) + 4 * half;
        int cc = n0 + qc + ct * 32 + l31;
        C[(size_t)rr * N + cc] = acc[rt][ct][reg];
      }
}

__global__ __launch_bounds__(256) void gemm_bt_sk2(
    const unsigned short* __restrict__ A, int lda,
    const unsigned short* __restrict__ BT,
    PtrPair parts, int Kc, int Ktot, int N) {
  float* C = blockIdx.z ? parts.p1 : parts.p0;
  gemm_sk_body(A, lda, BT, C, Kc, Ktot, N, blockIdx.z * Kc);
}

__global__ __launch_bounds__(256) void gemm_bt_sk4(
    const unsigned short* __restrict__ A, int lda,
    const unsigned short* __restrict__ BT,
    PtrQuad parts, int Kc, int Ktot, int N) {
  float* C = blockIdx.z == 0 ? parts.p0 : blockIdx.z == 1 ? parts.p1
           : blockIdx.z == 2 ? parts.p2 : parts.p3;
  gemm_sk_body(A, lda, BT, C, Kc, Ktot, N, blockIdx.z * Kc);
}

// out = p0 + p1 + p2 + p3 + resid  (f32, vectorized)
__global__ __launch_bounds__(256) void reduce4_k(
    const float4* __restrict__ P0, const float4* __restrict__ P1,
    const float4* __restrict__ P2, const float4* __restrict__ P3,
    const float4* __restrict__ R, float4* __restrict__ Out, int nvec) {
  int i = blockIdx.x * 256 + threadIdx.x;
  if (i >= nvec) return;
  float4 a = P0[i], b = P1[i], c = P2[i], d = P3[i], r = R[i];
  float4 o;
  o.x = a.x + b.x + c.x + d.x + r.x;
  o.y = a.y + b.y + c.y + d.y + r.y;
  o.z = a.z + b.z + c.z + d.z + r.z;
  o.w = a.w + b.w + c.w + d.w + r.w;
  Out[i] = o;
}

// ---------------------------------------------------------------------------
// reduce_norm_k: one row per block. h = p0+p1+resid; write Hres (f32);
// rmsnorm(h)*W -> Hin (bf16).
// ---------------------------------------------------------------------------
__global__ __launch_bounds__(256) void reduce_norm_k(
    const float4* __restrict__ P0, const float4* __restrict__ P1,
    const float4* __restrict__ R, float4* __restrict__ Hres,
    const float* __restrict__ W, unsigned short* __restrict__ Hin) {
  const int row = blockIdx.x;
  const int t = threadIdx.x;
  const int lane = t & 63, w = t >> 6;
  const int i = row * 256 + t;
  float4 a = P0[i], b = P1[i], r = R[i];
  float4 h;
  h.x = a.x + b.x + r.x;
  h.y = a.y + b.y + r.y;
  h.z = a.z + b.z + r.z;
  h.w = a.w + b.w + r.w;
  Hres[i] = h;
  float s = h.x * h.x + h.y * h.y + h.z * h.z + h.w * h.w;
#pragma unroll
  for (int m = 1; m < 64; m <<= 1) s += __shfl_xor(s, m, 64);
  __shared__ float red[4];
  if (lane == 0) red[w] = s;
  __syncthreads();
  float tot = red[0] + red[1] + red[2] + red[3];
  float inv = rsqrtf(tot * (1.0f / DMODEL) + 1e-6f);
  ushort4 o;
  o.x = f2bf(h.x * inv * W[t * 4 + 0]);
  o.y = f2bf(h.y * inv * W[t * 4 + 1]);
  o.z = f2bf(h.z * inv * W[t * 4 + 2]);
  o.w = f2bf(h.w * inv * W[t * 4 + 3]);
  *(ushort4*)(Hin + (size_t)row * DMODEL + t * 4) = o;
}

// ---------------------------------------------------------------------------
// Flash attention, swapped-QK^T 32x32 structure, no-max softmax, split-S.
// ---------------------------------------------------------------------------
__global__ __launch_bounds__(256) void attn_k(
    const unsigned short* __restrict__ QKV,
    const unsigned short* __restrict__ VtG,
    float* __restrict__ O0, float* __restrict__ O1,
    float* __restrict__ L) {
  const int h = blockIdx.y;
  const int qb = blockIdx.x;          // 0..15
  const int z = blockIdx.z;           // 0..1
  const int t = threadIdx.x;
  const int lane = t & 63;
  const int l31 = lane & 31, half = lane >> 5;
  const int w = t >> 6;               // wave 0..3
  const int q0 = qb * 128 + w * 32;
  const int kbase = z * 1024;
  const int gsw = (l31 & 7) ^ (l31 >> 3);

  __shared__ unsigned short Kt[2][64 * 64];
  __shared__ unsigned short Vt[2][64 * 64];

  const unsigned short* Kp = QKV + 1024 + h * 64;     // K columns of this head
  const unsigned short* Vg = VtG + (size_t)h * 64 * 2048;

  // Q fragments: lane holds Q[q0 + l31][ks*16 + half*8 .. +7]
  bf16x8 qf[4];
#pragma unroll
  for (int ks = 0; ks < 4; ++ks)
    qf[ks] = *(const bf16x8*)(QKV + (size_t)(q0 + l31) * 3072 + h * 64 + ks * 16 + half * 8);

  // prologue: stage tile 0 into buf 0
#pragma unroll
  for (int p = 0; p < 2; ++p) {
    int off = p * 2048 + t * 8;
    int r = off >> 6;
    int sc8 = (((off >> 3) & 7) ^ (r & 7) ^ ((r >> 3) & 3)) * 8;
    async16(Kp + (size_t)(kbase + r) * 3072 + sc8, &Kt[0][off]);
    async16(Vg + (size_t)r * 2048 + kbase + sc8, &Vt[0][off]);
  }
  asm volatile("s_waitcnt vmcnt(0)" ::: "memory");
  __syncthreads();

  f32x16 oacc[2] = {};
  float l_r = 0.f;

#pragma unroll 1
  for (int kt = 0; kt < 16; ++kt) {
    const int cur = kt & 1;
    // stage next tile into the other buffer (drained by end-of-iter barrier)
    if (kt + 1 < 16) {
      int kb2 = kbase + (kt + 1) * 64;
#pragma unroll
      for (int p = 0; p < 2; ++p) {
        int off = p * 2048 + t * 8;
        int r = off >> 6;
        int sc8 = (((off >> 3) & 7) ^ (r & 7) ^ ((r >> 3) & 3)) * 8;
        async16(Kp + (size_t)(kb2 + r) * 3072 + sc8, &Kt[cur ^ 1][off]);
        async16(Vg + (size_t)r * 2048 + kb2 + sc8, &Vt[cur ^ 1][off]);
      }
    }

    // QK^T (swapped): st[kblk] reg r = S[k = kblk*32+(r&3)+8*(r>>2)+4*half][q=l31]
    f32x16 st[2] = {};
#pragma unroll
    for (int ks = 0; ks < 4; ++ks) {
      const int ch = ((2 * ks + half) ^ gsw) * 8;
      bf16x8 k0 = *(const bf16x8*)&Kt[cur][l31 * 64 + ch];
      bf16x8 k1 = *(const bf16x8*)&Kt[cur][(32 + l31) * 64 + ch];
      st[0] = __builtin_amdgcn_mfma_f32_32x32x16_bf16(k0, qf[ks], st[0], 0, 0, 0);
      st[1] = __builtin_amdgcn_mfma_f32_32x32x16_bf16(k1, qf[ks], st[1], 0, 0, 0);
    }

    // no-max softmax: exp + per-lane partial row sum (partner half added at end)
    float psum = 0.f;
#pragma unroll
    for (int b = 0; b < 2; ++b)
#pragma unroll
      for (int r = 0; r < 16; ++r) {
        float e = __expf(st[b][r]);
        st[b][r] = e;
        psum += e;
      }
    l_r += psum;

    // pack P to bf16 pairs: group j=b*4+m covers k = 8j + 4*half + {0..3}
    unsigned int pklo[8], pkhi[8];
#pragma unroll
    for (int b = 0; b < 2; ++b)
#pragma unroll
      for (int m = 0; m < 4; ++m) {
        pklo[b * 4 + m] = pk_trunc(st[b][4 * m + 0], st[b][4 * m + 1]);
        pkhi[b * 4 + m] = pk_trunc(st[b][4 * m + 2], st[b][4 * m + 3]);
      }

    // PV: A-fragment lane supplies P[q=l31][16ks + 8*half + e] (group j*=2ks+half)
#pragma unroll
    for (int ks = 0; ks < 4; ++ks) {
      unsigned int keep_lo = half ? pklo[2 * ks + 1] : pklo[2 * ks];
      unsigned int keep_hi = half ? pkhi[2 * ks + 1] : pkhi[2 * ks];
      unsigned int pass_lo = half ? pklo[2 * ks] : pklo[2 * ks + 1];
      unsigned int pass_hi = half ? pkhi[2 * ks] : pkhi[2 * ks + 1];
      unsigned int olo = (unsigned int)__shfl_xor((int)pass_lo, 32, 64);
      unsigned int ohi = (unsigned int)__shfl_xor((int)pass_hi, 32, 64);
      unsigned int w0 = half ? olo : keep_lo;   // k offsets 0,1
      unsigned int w1 = half ? ohi : keep_hi;   // 2,3
      unsigned int w2 = half ? keep_lo : olo;   // 4,5
      unsigned int w3 = half ? keep_hi : ohi;   // 6,7
      bf16x8 af = mk_bf16x8(w0, w1, w2, w3);
      const int ch = ((2 * ks + half) ^ gsw) * 8;
      bf16x8 v0 = *(const bf16x8*)&Vt[cur][l31 * 64 + ch];
      bf16x8 v1 = *(const bf16x8*)&Vt[cur][(32 + l31) * 64 + ch];
      oacc[0] = __builtin_amdgcn_mfma_f32_32x32x16_bf16(af, v0, oacc[0], 0, 0, 0);
      oacc[1] = __builtin_amdgcn_mfma_f32_32x32x16_bf16(af, v1, oacc[1], 0, 0, 0);
    }

    __syncthreads();   // drains vmcnt+lgkm: next tile landed, reads done
  }

  float lt = l_r + __shfl_xor(l_r, 32, 64);
  float* Op = z ? O1 : O0;
#pragma unroll
  for (int db = 0; db < 2; ++db)
#pragma unroll
    for (int reg = 0; reg < 16; ++reg) {
      int q = (reg & 3) + 8 * (reg >> 2) + 4 * half;
      Op[(size_t)(q0 + q) * DMODEL + h * 64 + db * 32 + l31] = oacc[db][reg];
    }
  if (half == 0)
    L[(size_t)(h * 2 + z) * S_LEN + q0 + l31] = lt;
}

// Attn = bf16((O0+O1) / (l0+l1)); layout [s][h*64+d]
__global__ __launch_bounds__(256) void attn_combine_k(
    const float4* __restrict__ O0, const float4* __restrict__ O1,
    const float* __restrict__ L, unsigned short* __restrict__ Attn) {
  int i = blockIdx.x * 256 + threadIdx.x;
  int e0 = i * 4;
  int s = e0 >> 10;
  int c = e0 & 1023;
  int h = c >> 6;
  float la = L[(size_t)(h * 2) * S_LEN + s];
  float lb = L[(size_t)(h * 2 + 1) * S_LEN + s];
  float inv = 1.f / (la + lb);
  float4 a = O0[i], b = O1[i];
  ushort4 r;
  r.x = f2bf((a.x + b.x) * inv);
  r.y = f2bf((a.y + b.y) * inv);
  r.z = f2bf((a.z + b.z) * inv);
  r.w = f2bf((a.w + b.w) * inv);
  *(ushort4*)(Attn + e0) = r;
}

// ---------------------------------------------------------------------------
// Launch — 10 dispatches (R8 config restored; rope vectorized)
// ---------------------------------------------------------------------------
extern "C" void kernel_launch(void* const* d_in, const int* in_sizes, int n_in,
                              void* d_out, int out_size, void* d_ws, size_t ws_size,
                              hipStream_t stream) {
  (void)in_sizes; (void)n_in; (void)out_size; (void)ws_size;
  const float* x    = (const float*)d_in[0];
  const float* fcos = (const float*)d_in[1];
  const float* fsin = (const float*)d_in[2];
  const float* wq   = (const float*)d_in[3];
  const float* wk   = (const float*)d_in[4];
  const float* wv   = (const float*)d_in[5];
  const float* wo   = (const float*)d_in[6];
  const float* w1   = (const float*)d_in[7];
  const float* w2   = (const float*)d_in[8];
  const float* w3   = (const float*)d_in[9];
  const float* anw  = (const float*)d_in[10];
  const float* fnw  = (const float*)d_in[11];
  float* out = (float*)d_out;
  char* ws = (char*)d_ws;

  // ---- workspace layout (bytes), total 71,303,168 ----
  unsigned short* WqkvT = (unsigned short*)(ws + 0);
  unsigned short* VtG   = (unsigned short*)(ws + 0);
  float*          Lbuf  = (float*)(ws + 4194304);
  unsigned short* WoT   = (unsigned short*)(ws + 6291456);
  unsigned short* QKV   = (unsigned short*)(ws + 8388608);
  unsigned short* Attn  = (unsigned short*)(ws + 20971520);
  float* Oa             = (float*)(ws + 25165824);
  float* Ob             = (float*)(ws + 37748736);
  float* P0a            = (float*)(ws + 8388608);
  float* P1a            = (float*)(ws + 25165824);
  unsigned short* F     = (unsigned short*)(ws + 0);
  float* P0b            = (float*)(ws + 16777216);
  float* P1b            = (float*)(ws + 25165824);
  float* P2b            = (float*)(ws + 46137344);   // W13I region, dead after gemm256
  float* P3b            = (float*)(ws + 54525952);   // ends exactly at W2T
  unsigned short* Hin   = (unsigned short*)(ws + 33554432);
  float*          Hres  = (float*)        (ws + 37748736);
  unsigned short* W13I  = (unsigned short*)(ws + 46137344);
  unsigned short* W2T   = (unsigned short*)(ws + 62914560);

  // 1. fused weight transposes + rmsnorm(x)->Hin
  prep_k<<<6144, 256, 0, stream>>>(PrepArgs{
      wq, wk, wv, wo, w1, w3, w2, x, anw,
      WqkvT, WoT, W13I, W2T, Hin});

  // attention branch
  gemm_bt<0><<<dim3(24, 16), 256, 0, stream>>>(Hin, 1024, WqkvT, QKV, 1024, 3072);
  rope_vtrans_k<<<1536, 256, 0, stream>>>(QKV, fcos, fsin, VtG);
  attn_k<<<dim3(16, 16, 2), 256, 0, stream>>>(QKV, VtG, Oa, Ob, Lbuf);
  attn_combine_k<<<2048, 256, 0, stream>>>((const float4*)Oa, (const float4*)Ob, Lbuf, Attn);
  gemm_bt_sk2<<<dim3(8, 16, 2), 256, 0, stream>>>(Attn, 1024, WoT, PtrPair{P0a, P1a}, 512, 1024, 1024);
  reduce_norm_k<<<2048, 256, 0, stream>>>((const float4*)P0a, (const float4*)P1a,
                                          (const float4*)x, (float4*)Hres, fnw, Hin);

  // ffn branch
  gemm256_silu<<<dim3(256), 512, 0, stream>>>(Hin, W13I, F);
  gemm_bt_sk4<<<dim3(8, 16, 4), 256, 0, stream>>>(F, 4096, W2T,
      PtrQuad{P0b, P1b, P2b, P3b}, 1024, 4096, 1024);
  reduce4_k<<<2048, 256, 0, stream>>>((const float4*)P0b, (const float4*)P1b,
                                      (const float4*)P2b, (const float4*)P3b,
                                      (const float4*)Hres, (float4*)out, 524288);
}